// Round 2
// baseline (1663.771 us; speedup 1.0000x reference)
//
#include <hip/hip_runtime.h>

// ---------------- problem dims ----------------
#define NE   200000
#define DC   64
#define DL   256
#define DD   128
#define FEAT 320          // 2*DD + DC
#define IND  449          // FEAT + DD + 1
#define DH   80
#define BB   32
#define TT   64
#define NEV  2048         // BB*TT
#define HSZ  8192         // hash slots (power of 2, >= 2*max distinct touched entities)
#define MAXFIX 6

typedef __attribute__((ext_vector_type(8))) short  short8;
typedef __attribute__((ext_vector_type(4))) float  floatx4;

__device__ __forceinline__ unsigned short f2bf(float x) {
    unsigned u = __float_as_uint(x);
    u += 0x7fffu + ((u >> 16) & 1u);        // RNE
    return (unsigned short)(u >> 16);
}
__device__ __forceinline__ float sigmoidf_(float x) { return 1.0f / (1.0f + __expf(-x)); }

// hash: volatile global (L2-resident 64KB); single-CU user so L1 staleness avoided via sc0.
__device__ __forceinline__ int hash_lookup(volatile int* hk, volatile float* ht, int v, float* out) {
    unsigned h = ((unsigned)v * 2654435761u) >> 19;
    while (true) {
        int k = hk[h];
        if (k == v) { *out = ht[h]; return 1; }
        if (k == -1) return 0;
        h = (h + 1) & (HSZ - 1);
    }
}
__device__ __forceinline__ void hash_insert(volatile int* hk, volatile float* ht, int v, float tv) {
    unsigned h = ((unsigned)v * 2654435761u) >> 19;
    while (true) {
        int k = hk[h];
        if (k == v) { ht[h] = tv; return; }
        if (k == -1) {
            int old = atomicCAS((int*)hk + h, -1, v);
            if (old == -1 || old == v) { ht[h] = tv; return; }
            continue;  // someone else claimed; re-examine same slot
        }
        h = (h + 1) & (HSZ - 1);
    }
}

// ---------------- prep: W_hh^T -> bf16 ----------------
__global__ __launch_bounds__(256)
void transpose_whh(const float* __restrict__ W_hh, unsigned short* __restrict__ whht) {
    int idx = blockIdx.x * 256 + threadIdx.x;     // 32768 = DD*DL
    int d = idx >> 8, l = idx & 255;
    whht[d * DL + l] = f2bf(W_hh[l * DD + d]);
}

// ---------------- prep: Zsum/Zs/Zo (t-major) + evt rel section ----------------
__global__ __launch_bounds__(256)
void precompute_z(const int* __restrict__ seq_s, const int* __restrict__ seq_o,
                  const int* __restrict__ seq_r, const float* __restrict__ mem0,
                  const float* __restrict__ rel_emb, const float* __restrict__ W_hidden,
                  float* __restrict__ Zsum, float* __restrict__ Zs, float* __restrict__ Zo,
                  float* __restrict__ evt) {
    __shared__ float as_[8][DD], ao_[8][DD], ar_[8][DC];
    int e0 = blockIdx.x * 8;
    int tid = threadIdx.x;
    for (int i = tid; i < 8 * DD; i += 256) {
        int r = i >> 7, d = i & 127;
        as_[r][d] = mem0[(size_t)seq_s[e0 + r] * DD + d];
        ao_[r][d] = mem0[(size_t)seq_o[e0 + r] * DD + d];
    }
    for (int i = tid; i < 8 * DC; i += 256) {
        int r = i >> 6, c = i & 63;
        ar_[r][c] = rel_emb[(size_t)seq_r[e0 + r] * DC + c];
    }
    __syncthreads();
    int l = tid;  // 0..255
    float accs[8] = {0}, acco[8] = {0}, accr[8] = {0};
    for (int d = 0; d < DD; ++d) {
        float w1 = W_hidden[d * DL + l];
        float w2 = W_hidden[(DD + d) * DL + l];
#pragma unroll
        for (int r = 0; r < 8; ++r) { accs[r] += as_[r][d] * w1; acco[r] += ao_[r][d] * w2; }
    }
    for (int c = 0; c < DC; ++c) {
        float w3 = W_hidden[(2 * DD + c) * DL + l];
#pragma unroll
        for (int r = 0; r < 8; ++r) accr[r] += ar_[r][c] * w3;
    }
    for (int r = 0; r < 8; ++r) {
        int e = e0 + r, b = e >> 6, tt = e & 63;
        size_t idx = (size_t)(tt * BB + b) * DL + l;     // t-major
        Zs[idx] = accs[r]; Zo[idx] = acco[r];
        Zsum[idx] = accs[r] + acco[r] + accr[r];
    }
    // evt relation section (scan-independent)
    for (int i = tid; i < 8 * DC; i += 256) {
        int r = i >> 6, c = i & 63;
        evt[(size_t)(e0 + r) * FEAT + 2 * DD + c] = ar_[r][c];
    }
}

// ---------------- phase 1: sequential scan (single workgroup) ----------------
__global__ __launch_bounds__(512)
void phase1(const int* __restrict__ seq_s, const int* __restrict__ seq_o,
            const int* __restrict__ seq_r, const float* __restrict__ seq_t,
            const float* __restrict__ lt0, const float* __restrict__ W_hidden,
            const float* __restrict__ W_st, const float* __restrict__ W_ot,
            const float* __restrict__ Zsum, const float* __restrict__ Zs,
            const float* __restrict__ Zo, const unsigned short* __restrict__ whht,
            float* __restrict__ memo, float* __restrict__ lt_out,
            float* __restrict__ evt,
            volatile int* hkey, volatile float* htime) {
    __shared__ unsigned short h_bf[BB * DL];      // 16 KB, XOR-swizzled groups of 8
    __shared__ float ns_[BB * 132];               // 16.5 KB
    __shared__ float no_[BB * 132];               // 16.5 KB
    __shared__ float fixbuf[MAXFIX][DL];          // 6 KB
    __shared__ float mrow[MAXFIX][DD];            // 3 KB
    __shared__ int   sEnt[2][64];
    __shared__ float sT[2][BB], sDs[2][BB], sDo[2][BB];
    __shared__ int   sFixS[2][BB], sFixO[2][BB];
    __shared__ int   sWin[64];
    __shared__ int   wlB[2][MAXFIX], wlSide[2][MAXFIX], wlEnt[2][MAXFIX];
    __shared__ int   sNd[2];

    const int tid  = threadIdx.x;
    const int lane = tid & 63;
    const int wv   = tid >> 6;         // 0..7
    const int mtile = wv >> 2;         // 0..1
    const int nt0   = (wv & 3) * 2;    // ntiles nt0, nt0+1
    const int mr_   = lane & 15;
    const int quad  = lane >> 4;
    const int zb = tid >> 4, zj = tid & 15;   // SB mapping: b, 16-l group

    // Preload B fragments (W_hh^T bf16): stays in regs all steps.
    short8 bfrag[2][8];
#pragma unroll
    for (int nt = 0; nt < 2; ++nt) {
        int d = (nt0 + nt) * 16 + mr_;
#pragma unroll
        for (int ks = 0; ks < 8; ++ks)
            bfrag[nt][ks] = *(const short8*)&whht[d * DL + ks * 32 + quad * 8];
    }

    // ---- prologue: prep t=0 (hash empty -> all clean) + z prefetch ----
    if (tid < 64) {
        int cand = tid, b = cand & 31, side = cand >> 5;
        int v = (side ? seq_o : seq_s)[b * TT];
        sEnt[0][cand] = v;
        float tv = seq_t[b * TT];
        float dt = tv - lt0[v];
        if (side == 0) { sT[0][b] = tv; sDs[0][b] = dt; sFixS[0][b] = -1; }
        else           { sDo[0][b] = dt; sFixO[0][b] = -1; }
    }
    if (tid == 0) sNd[0] = 0;
    float zn[16];
    {
        const float* p = &Zsum[(size_t)zb * DL + zj * 16];
#pragma unroll
        for (int i = 0; i < 16; ++i) zn[i] = p[i];
    }
    __syncthreads();

    for (int t = 0; t < TT; ++t) {
        const int cur = t & 1, nxt = cur ^ 1;

        // ---- SA: wave-parallel dirty fixups (rare) ----
        int nfix = sNd[cur]; if (nfix > MAXFIX) nfix = MAXFIX;
        if (nfix > 0) {
            if (wv < nfix && lane < 32) {
                int v = wlEnt[cur][wv];
                *(floatx4*)&mrow[wv][lane * 4] = *(const floatx4*)&memo[(size_t)v * DD + lane * 4];
            }
            __syncthreads();
            if (wv < nfix) {
                int side = wlSide[cur][wv];
                const float* W = W_hidden + (size_t)(side ? DD : 0) * DL + lane * 4;
                floatx4 acc = {0.f, 0.f, 0.f, 0.f};
#pragma unroll 4
                for (int d = 0; d < DD; ++d) {
                    float m = mrow[wv][d];
                    floatx4 w4 = *(const floatx4*)&W[(size_t)d * DL];
                    acc += m * w4;
                }
                *(floatx4*)&fixbuf[wv][lane * 4] = acc;
            }
            __syncthreads();
        }

        // ---- SB: z (+fixes) -> h = sigmoid -> bf16 swizzled LDS; prefetch; winner+insert ----
        {
            float zc[16];
#pragma unroll
            for (int i = 0; i < 16; ++i) zc[i] = zn[i];
            int fs = sFixS[cur][zb];
            if (fs >= 0) {
                const float* zsrc = &Zs[(size_t)(t * BB + zb) * DL + zj * 16];
#pragma unroll
                for (int i = 0; i < 16; ++i) zc[i] += fixbuf[fs][zj * 16 + i] - zsrc[i];
            } else if (fs == -2) {   // overflow slow path
                const float* zsrc = &Zs[(size_t)(t * BB + zb) * DL + zj * 16];
                const float* mr2 = &memo[(size_t)sEnt[cur][zb] * DD];
                float fr[16];
#pragma unroll
                for (int i = 0; i < 16; ++i) fr[i] = -zsrc[i];
                for (int d = 0; d < DD; ++d) {
                    float a = mr2[d];
                    const float* wr = &W_hidden[d * DL + zj * 16];
#pragma unroll
                    for (int i = 0; i < 16; ++i) fr[i] += a * wr[i];
                }
#pragma unroll
                for (int i = 0; i < 16; ++i) zc[i] += fr[i];
            }
            int fo = sFixO[cur][zb];
            if (fo >= 0) {
                const float* zsrc = &Zo[(size_t)(t * BB + zb) * DL + zj * 16];
#pragma unroll
                for (int i = 0; i < 16; ++i) zc[i] += fixbuf[fo][zj * 16 + i] - zsrc[i];
            } else if (fo == -2) {
                const float* zsrc = &Zo[(size_t)(t * BB + zb) * DL + zj * 16];
                const float* mr2 = &memo[(size_t)sEnt[cur][32 + zb] * DD];
                float fr[16];
#pragma unroll
                for (int i = 0; i < 16; ++i) fr[i] = -zsrc[i];
                for (int d = 0; d < DD; ++d) {
                    float a = mr2[d];
                    const float* wr = &W_hidden[(DD + d) * DL + zj * 16];
#pragma unroll
                    for (int i = 0; i < 16; ++i) fr[i] += a * wr[i];
                }
#pragma unroll
                for (int i = 0; i < 16; ++i) zc[i] += fr[i];
            }
            unsigned short hv[16];
#pragma unroll
            for (int i = 0; i < 16; ++i) hv[i] = f2bf(sigmoidf_(zc[i]));
            int g0 = (2 * zj) ^ (zb & 7);
            int g1 = (2 * zj + 1) ^ (zb & 7);
            short8 v0, v1;
#pragma unroll
            for (int i = 0; i < 8; ++i) { v0[i] = (short)hv[i]; v1[i] = (short)hv[8 + i]; }
            *(short8*)&h_bf[zb * DL + g0 * 8] = v0;
            *(short8*)&h_bf[zb * DL + g1 * 8] = v1;
            // prefetch next step's z into regs (no dependency -> latency hidden)
            int tn = (t + 1 < TT) ? (t + 1) : (TT - 1);
            const float* p = &Zsum[(size_t)(tn * BB + zb) * DL + zj * 16];
#pragma unroll
            for (int i = 0; i < 16; ++i) zn[i] = p[i];
        }
        // winner resolution (last candidate wins: o-phase after s-phase, higher b wins) + hash insert
        if (tid < 64) {
            int cand = tid, v = sEnt[cur][cand];
            int win = 1;
            for (int c2 = cand + 1; c2 < 64; ++c2)
                if (sEnt[cur][c2] == v) { win = 0; break; }
            sWin[cand] = win;
            if (win) hash_insert(hkey, htime, v, sT[cur][cand & 31]);
        }
        if (tid == 0) sNd[nxt] = 0;
        __syncthreads();

        // ---- SC: hh = h @ W_hh via bf16 MFMA; new_s/new_o = sigmoid(dt*W + hh) ----
        {
            floatx4 acc0 = {0.f, 0.f, 0.f, 0.f}, acc1 = {0.f, 0.f, 0.f, 0.f};
            int ab = mtile * 16 + mr_;
#pragma unroll
            for (int ks = 0; ks < 8; ++ks) {
                int gp = (ks * 4 + quad) ^ (ab & 7);
                short8 afrag = *(const short8*)&h_bf[ab * DL + gp * 8];
                acc0 = __builtin_amdgcn_mfma_f32_16x16x32_bf16(afrag, bfrag[0][ks], acc0, 0, 0, 0);
                acc1 = __builtin_amdgcn_mfma_f32_16x16x32_bf16(afrag, bfrag[1][ks], acc1, 0, 0, 0);
            }
#pragma unroll
            for (int nt = 0; nt < 2; ++nt) {
                floatx4 acc = nt ? acc1 : acc0;
                int d = (nt0 + nt) * 16 + mr_;
                float wst = W_st[d], wot = W_ot[d];
#pragma unroll
                for (int reg = 0; reg < 4; ++reg) {
                    int b = mtile * 16 + quad * 4 + reg;
                    float hh = acc[reg];
                    ns_[b * 132 + d] = sigmoidf_(sDs[cur][b] * wst + hh);
                    no_[b * 132 + d] = sigmoidf_(sDo[cur][b] * wot + hh);
                }
            }
        }
        __syncthreads();

        // ---- SD: scatter memo + evt write + prep t+1 ----
#pragma unroll
        for (int k2 = 0; k2 < 4; ++k2) {
            int i4 = tid + k2 * 512;           // 0..2047
            int cand = i4 >> 5, c4 = i4 & 31;
            if (sWin[cand]) {
                int v = sEnt[cur][cand];
                const float* src = (cand < 32 ? ns_ : no_) + (cand & 31) * 132 + c4 * 4;
                *(floatx4*)&memo[(size_t)v * DD + c4 * 4] = *(const floatx4*)src;
            }
        }
#pragma unroll
        for (int k2 = 0; k2 < 4; ++k2) {
            int i4 = tid + k2 * 512;           // 0..2047
            int b = i4 >> 6, c4 = i4 & 63;
            const float* src = (c4 < 32) ? &ns_[b * 132 + c4 * 4] : &no_[b * 132 + (c4 - 32) * 4];
            *(floatx4*)&evt[(size_t)(b * TT + t) * FEAT + c4 * 4] = *(const floatx4*)src;
        }
        if (t + 1 < TT && tid < 64) {
            int cand = tid, b = cand & 31, side = cand >> 5;
            int tn = t + 1;
            int v = (side ? seq_o : seq_s)[b * TT + tn];
            sEnt[nxt][cand] = v;
            float tv = seq_t[b * TT + tn];
            if (side == 0) sT[nxt][b] = tv;
            float ltv; int hit = hash_lookup(hkey, htime, v, &ltv);
            if (!hit) ltv = lt0[v];
            float dt = tv - ltv;
            int fi = -1;
            if (hit) {
                int w = atomicAdd(&sNd[nxt], 1);
                if (w < MAXFIX) { wlB[nxt][w] = b; wlSide[nxt][w] = side; wlEnt[nxt][w] = v; fi = w; }
                else fi = -2;
            }
            if (side == 0) { sDs[nxt][b] = dt; sFixS[nxt][b] = fi; }
            else           { sDo[nxt][b] = dt; sFixO[nxt][b] = fi; }
        }
        __syncthreads();
    }

    // ---- epilogue: dump latest_time updates from hash ----
    for (int sidx = tid; sidx < HSZ; sidx += 512) {
        int k = hkey[sidx];
        if (k >= 0) lt_out[k] = htime[sidx];
    }
}

// ---------------- phase 2 ----------------
__global__ __launch_bounds__(128)
void build_e(const float* __restrict__ src, const float* __restrict__ seq_t,
             float* __restrict__ ebuf) {
    int e = blockIdx.x;
    float tv = seq_t[e];
    const float* s = &src[(size_t)e * FEAT];
    float* dst = &ebuf[(size_t)e * IND];
    for (int f = threadIdx.x; f < IND; f += 128) {
        float v;
        if (f < FEAT) v = s[f];
        else if (f < FEAT + DD) {
            int d = f - FEAT;
            float denom = __powf(10000.0f, (float)d);   // inf for d>=10 -> norm 0 (matches ref)
            v = sinf(tv * (1.0f / denom));
        } else v = 1.0f;
        dst[f] = v;
    }
}

__global__ __launch_bounds__(256)
void proj(const float* __restrict__ ebuf, const float* __restrict__ Wq,
          const float* __restrict__ Wk, const float* __restrict__ Wv,
          float* __restrict__ q, float* __restrict__ k, float* __restrict__ v) {
    __shared__ float at[32][IND];
    int tid = threadIdx.x;
    int r0b = blockIdx.x * 32;
    for (int i = tid; i < 32 * IND; i += 256) {
        int r = i / IND, c = i - r * IND;
        at[r][c] = ebuf[(size_t)(r0b + r) * IND + c];
    }
    __syncthreads();
    const float* W = (blockIdx.z == 0) ? Wq : (blockIdx.z == 1) ? Wk : Wv;
    float* out = (blockIdx.z == 0) ? q : (blockIdx.z == 1) ? k : v;
    int colg = tid & 15, rowg = tid >> 4;
    int c0 = blockIdx.y * 64 + colg * 4;
    int r0 = rowg * 2;
    floatx4 acc0 = {0.f, 0.f, 0.f, 0.f}, acc1 = {0.f, 0.f, 0.f, 0.f};
    for (int kk = 0; kk < IND; ++kk) {
        floatx4 w = *(const floatx4*)&W[(size_t)kk * FEAT + c0];
        float a0 = at[r0][kk], a1 = at[r0 + 1][kk];
        acc0 += a0 * w;
        acc1 += a1 * w;
    }
    *(floatx4*)&out[(size_t)(r0b + r0) * FEAT + c0]     = acc0;
    *(floatx4*)&out[(size_t)(r0b + r0 + 1) * FEAT + c0] = acc1;
}

__global__ __launch_bounds__(256)
void attn(const float* __restrict__ q, const float* __restrict__ k,
          const float* __restrict__ v, float* __restrict__ ao) {
    __shared__ float qs[TT][DH], ks[TT][DH], vs[TT][DH];
    __shared__ float sc[TT][TT + 1];
    int bh = blockIdx.x;
    int b = bh >> 2, h = bh & 3;
    int tid = threadIdx.x;
    for (int i = tid; i < TT * DH; i += 256) {
        int r = i / DH, d = i - r * DH;
        size_t base = (size_t)(b * TT + r) * FEAT + h * DH + d;
        qs[r][d] = q[base]; ks[r][d] = k[base]; vs[r][d] = v[base];
    }
    __syncthreads();
    const float scale = 0.11180339887498949f;   // 1/sqrt(80)
    for (int idx = tid; idx < TT * TT; idx += 256) {
        int i = idx >> 6, j = idx & 63;
        float s = 0.f;
        for (int d = 0; d < DH; ++d) s += qs[i][d] * ks[j][d];
        sc[i][j] = s * scale;
    }
    __syncthreads();
    if (tid < TT) {
        int i = tid;
        if (i == 0) {
            for (int j = 0; j < TT; ++j) sc[0][j] = 0.0f;
        } else {
            float m = -1e30f;
            for (int j = 0; j < i; ++j) m = fmaxf(m, sc[i][j]);
            float sum = 0.f;
            for (int j = 0; j < i; ++j) { float p = __expf(sc[i][j] - m); sc[i][j] = p; sum += p; }
            float inv = 1.0f / sum;
            for (int j = 0; j < i; ++j) sc[i][j] *= inv;
            for (int j = i; j < TT; ++j) sc[i][j] = 0.0f;
        }
    }
    __syncthreads();
    for (int idx = tid; idx < TT * DH; idx += 256) {
        int i = idx / DH, d = idx - i * DH;
        float s = 0.f;
        for (int j = 0; j < TT; ++j) s += sc[i][j] * vs[j][d];
        ao[(size_t)(b * TT + i) * FEAT + h * DH + d] = s;
    }
}

__global__ __launch_bounds__(256)
void outproj(const float* __restrict__ ain, const float* __restrict__ Wo,
             const float* __restrict__ resid, float* __restrict__ xout) {
    __shared__ float at[32][FEAT];
    int tid = threadIdx.x;
    int r0b = blockIdx.x * 32;
    for (int i = tid; i < 32 * FEAT; i += 256) {
        int r = i / FEAT, c = i - r * FEAT;
        at[r][c] = ain[(size_t)(r0b + r) * FEAT + c];
    }
    __syncthreads();
    int colg = tid & 15, rowg = tid >> 4;
    int c0 = blockIdx.y * 64 + colg * 4;
    int r0 = rowg * 2;
    floatx4 acc0 = {0.f, 0.f, 0.f, 0.f}, acc1 = {0.f, 0.f, 0.f, 0.f};
    for (int kk = 0; kk < FEAT; ++kk) {
        floatx4 w = *(const floatx4*)&Wo[(size_t)kk * FEAT + c0];
        float a0 = at[r0][kk], a1 = at[r0 + 1][kk];
        acc0 += a0 * w;
        acc1 += a1 * w;
    }
#pragma unroll
    for (int rr = 0; rr < 2; ++rr) {
        int row = r0b + r0 + rr;
        floatx4 a = rr ? acc1 : acc0;
        floatx4 res = *(const floatx4*)&resid[(size_t)row * FEAT + c0];
        floatx4 o;
#pragma unroll
        for (int i = 0; i < 4; ++i) o[i] = res[i] + tanhf(a[i]);
        *(floatx4*)&xout[(size_t)row * FEAT + c0] = o;
    }
}

__global__ __launch_bounds__(128)
void score_k(const float* __restrict__ x, const float* __restrict__ W1,
             const float* __restrict__ b1, const float* __restrict__ W2,
             const float* __restrict__ b2, float* __restrict__ lam_out,
             float* __restrict__ lossbuf) {
    __shared__ float xr[FEAT];
    __shared__ float red[2];
    int e = blockIdx.x;
    int tid = threadIdx.x;
    for (int f = tid; f < FEAT; f += 128) xr[f] = x[(size_t)e * FEAT + f];
    __syncthreads();
    int d = tid;
    float acc = b1[d];
    for (int kk = 0; kk < FEAT; ++kk) acc += xr[kk] * W1[kk * DD + d];
    acc = fmaxf(acc, 0.0f) * W2[d];
    for (int off = 32; off; off >>= 1) acc += __shfl_down(acc, off, 64);
    if ((tid & 63) == 0) red[tid >> 6] = acc;
    __syncthreads();
    if (tid == 0) {
        float s = red[0] + red[1] + b2[0];
        float lam = fmaxf(s, 0.0f) + log1pf(expf(-fabsf(s)));   // softplus
        lam_out[e] = lam;
        lossbuf[e] = -logf(lam + 1e-8f);
    }
}

__global__ __launch_bounds__(1024)
void loss_reduce(const float* __restrict__ lossbuf, float* __restrict__ out0) {
    __shared__ float red[16];
    int tid = threadIdx.x;
    float s = 0.f;
    for (int i = tid; i < NEV; i += 1024) s += lossbuf[i];
    for (int off = 32; off; off >>= 1) s += __shfl_down(s, off, 64);
    if ((tid & 63) == 0) red[tid >> 6] = s;
    __syncthreads();
    if (tid == 0) {
        float tot = 0.f;
        for (int i = 0; i < 16; ++i) tot += red[i];
        out0[0] = tot * (1.0f / 2048.0f);
    }
}

// ---------------- launch ----------------
extern "C" void kernel_launch(void* const* d_in, const int* in_sizes, int n_in,
                              void* d_out, int out_size, void* d_ws, size_t ws_size,
                              hipStream_t stream) {
    const int*   seq_s = (const int*)d_in[0];
    const int*   seq_o = (const int*)d_in[1];
    const int*   seq_r = (const int*)d_in[2];
    const float* seq_t = (const float*)d_in[3];
    const float* mem0  = (const float*)d_in[4];
    const float* lt0   = (const float*)d_in[5];
    const float* rel   = (const float*)d_in[6];
    const float* W_hidden = (const float*)d_in[7];
    const float* W_hh  = (const float*)d_in[8];
    const float* W_st  = (const float*)d_in[9];
    const float* W_ot  = (const float*)d_in[10];
    const float* Wq    = (const float*)d_in[11];
    const float* Wk    = (const float*)d_in[12];
    const float* Wv    = (const float*)d_in[13];
    const float* Wo    = (const float*)d_in[14];
    const float* sW1   = (const float*)d_in[15];
    const float* sb1   = (const float*)d_in[16];
    const float* sW2   = (const float*)d_in[17];
    const float* sb2   = (const float*)d_in[18];

    float* out      = (float*)d_out;
    float* out_lam  = out + 1;
    float* out_mem  = out + 2049;
    float* out_lt   = out + 2049 + (size_t)NE * DD;

    float* ws = (float*)d_ws;
    float* evt   = ws;                       // 655360
    float* xbuf  = ws + 655360;              // 655360
    float* Zsum  = ws + 1310720;             // 524288 }  Z region reused as ebuf
    float* Zs    = ws + 1835008;             // 524288 }  in phase 2 (1.57M >= 919552)
    float* Zo    = ws + 2359296;             // 524288 }
    float* ebuf  = ws + 1310720;
    float* qbuf  = ws + 2883584;             // 655360
    float* kbuf  = ws + 3538944;             // 655360
    float* vbuf  = ws + 4194304;             // 655360
    float* aobuf = ws + 4849664;             // 655360
    float* lossb = ws + 5505024;             // 2048
    unsigned short* whht = (unsigned short*)(ws + 5507072);   // DD*DL bf16 (16384 floats)
    int*   hkey  = (int*)(ws + 5523456);     // HSZ ints
    float* htime = ws + 5531648;             // HSZ floats

    // Materialize mem / latest_time outputs (updated in place by phase1).
    hipMemcpyAsync(out_mem, mem0, (size_t)NE * DD * sizeof(float), hipMemcpyDeviceToDevice, stream);
    hipMemcpyAsync(out_lt,  lt0,  (size_t)NE * sizeof(float),      hipMemcpyDeviceToDevice, stream);
    hipMemsetAsync(hkey, 0xFF, (size_t)HSZ * sizeof(int), stream);  // keys = -1

    transpose_whh<<<128, 256, 0, stream>>>(W_hh, whht);
    precompute_z<<<NEV / 8, 256, 0, stream>>>(seq_s, seq_o, seq_r, mem0, rel, W_hidden,
                                              Zsum, Zs, Zo, evt);
    phase1<<<1, 512, 0, stream>>>(seq_s, seq_o, seq_r, seq_t, lt0, W_hidden, W_st, W_ot,
                                  Zsum, Zs, Zo, whht, out_mem, out_lt, evt, hkey, htime);

    for (int l = 0; l < 2; ++l) {
        const float* src = l ? xbuf : evt;
        build_e<<<NEV, 128, 0, stream>>>(src, seq_t, ebuf);
        proj<<<dim3(64, 5, 3), 256, 0, stream>>>(ebuf,
                                                 Wq + (size_t)l * IND * FEAT,
                                                 Wk + (size_t)l * IND * FEAT,
                                                 Wv + (size_t)l * IND * FEAT,
                                                 qbuf, kbuf, vbuf);
        attn<<<128, 256, 0, stream>>>(qbuf, kbuf, vbuf, aobuf);
        outproj<<<dim3(64, 5), 256, 0, stream>>>(aobuf, Wo + (size_t)l * FEAT * FEAT, src, xbuf);
    }
    score_k<<<NEV, 128, 0, stream>>>(xbuf, sW1, sb1, sW2, sb2, out_lam, lossb);
    loss_reduce<<<1, 1024, 0, stream>>>(lossb, out);
}

// Round 3
// 977.069 us; speedup vs baseline: 1.7028x; 1.7028x over previous
//
#include <hip/hip_runtime.h>

// ---------------- problem dims ----------------
#define NE   200000
#define DC   64
#define DL   256
#define DD   128
#define FEAT 320          // 2*DD + DC
#define IND  449          // FEAT + DD + 1
#define DH   80
#define BB   32
#define TT   64
#define NEV  2048         // BB*TT
#define NSLOT 4096

typedef __attribute__((ext_vector_type(4))) float  floatx4;

__device__ __forceinline__ float sigmoidf_(float x) { return 1.0f / (1.0f + __expf(-x)); }

// ---------------- K1: slot analysis (prev-toucher, dt, winner, fix list) ----------------
// slot = t*64 + side*32 + b  (key order = scatter order: later step > o > s > higher b)
__global__ __launch_bounds__(256)
void slot_analyze(const int* __restrict__ seq_s, const int* __restrict__ seq_o,
                  const float* __restrict__ seq_time, const float* __restrict__ lt0,
                  float* __restrict__ slotDt, int* __restrict__ slotPrev,
                  int* __restrict__ slotWin, int* __restrict__ fixList,
                  int* __restrict__ fixState, int* __restrict__ evFixIdx,
                  int* __restrict__ fixCnt) {
    __shared__ int entL[NSLOT];
    __shared__ unsigned char collL[256];
    int tid = threadIdx.x;
    for (int j = tid; j < NSLOT; j += 256) {
        int b = j & 31, side = (j >> 5) & 1, t = j >> 6;
        entL[j] = (side ? seq_o : seq_s)[b * TT + t];
    }
    __syncthreads();
    int slot = blockIdx.x * 256 + tid;
    int b = slot & 31, side = (slot >> 5) & 1, t = slot >> 6;
    int myent = entL[slot];
    int win = 1, best = -1;
#pragma unroll 8
    for (int j = 0; j < NSLOT; ++j) {
        if (entL[j] == myent) {
            if (j > slot) win = 0;
            else if ((j >> 6) < t) best = j;   // j ascending -> keeps max key among prior steps
        }
    }
    float tv = seq_time[b * TT + t];
    float pt = (best >= 0) ? seq_time[(best & 31) * TT + (best >> 6)] : lt0[myent];
    slotDt[slot]  = tv - pt;
    slotPrev[slot] = best;
    slotWin[slot]  = win;
    collL[tid] = (best >= 0) ? 1 : 0;
    __syncthreads();
    if (side == 0) {      // one thread per event; o-slot is tid+32 (same block)
        int e = b * TT + t;
        int c = collL[tid] | collL[tid + 32];
        int idx = -1;
        if (c) { idx = atomicAdd(fixCnt, 1); fixList[idx] = e; fixState[idx] = -1; }
        evFixIdx[e] = idx;
    }
}

// ---------------- K2: all-events parallel RNN compute (fp32) ----------------
__global__ __launch_bounds__(256)
void event_compute(const int* __restrict__ seq_s, const int* __restrict__ seq_o,
                   const int* __restrict__ seq_r, const float* __restrict__ seq_time,
                   const float* __restrict__ mem0, const float* __restrict__ rel,
                   const float* __restrict__ W_hidden, const float* __restrict__ W_hh,
                   const float* __restrict__ W_st, const float* __restrict__ W_ot,
                   const float* __restrict__ slotDt,
                   float* __restrict__ evt, float* __restrict__ ebuf,
                   float* __restrict__ tebuf) {
    __shared__ float xc[8][FEAT];
    __shared__ float hs[8][DL];
    __shared__ int   sSi[8], sOi[8], sRi[8];
    __shared__ float sDs[8], sDo[8], sTv[8];
    int tid = threadIdx.x;
    int e0 = blockIdx.x * 8;
    if (tid < 8) {
        int e = e0 + tid;
        sSi[tid] = seq_s[e]; sOi[tid] = seq_o[e]; sRi[tid] = seq_r[e];
        int b = e >> 6, t = e & 63;
        sDs[tid] = slotDt[t * 64 + b];
        sDo[tid] = slotDt[t * 64 + 32 + b];
        sTv[tid] = seq_time[e];
    }
    __syncthreads();
    for (int i = tid; i < 8 * FEAT; i += 256) {
        int r = i / FEAT, k = i - r * FEAT;
        float v;
        if (k < DD)            v = mem0[(size_t)sSi[r] * DD + k];
        else if (k < 2 * DD)   v = mem0[(size_t)sOi[r] * DD + (k - DD)];
        else                   v = rel[(size_t)sRi[r] * DC + (k - 2 * DD)];
        xc[r][k] = v;
    }
    __syncthreads();
    {   // z = xc @ W_hidden ; h = sigmoid(z)
        int j = tid;
        float acc[8] = {0.f,0.f,0.f,0.f,0.f,0.f,0.f,0.f};
        for (int k = 0; k < FEAT; ++k) {
            float w = W_hidden[(size_t)k * DL + j];
#pragma unroll
            for (int r = 0; r < 8; ++r) acc[r] += xc[r][k] * w;
        }
#pragma unroll
        for (int r = 0; r < 8; ++r) hs[r][j] = sigmoidf_(acc[r]);
    }
    __syncthreads();
    {   // hh = h @ W_hh ; ns/no = sigmoid(dt*W + hh)
        int d = tid & 127, grp = tid >> 7;     // grp 0 -> events 0..3, grp 1 -> 4..7
        float acc[4] = {0.f,0.f,0.f,0.f};
        for (int l = 0; l < DL; ++l) {
            float w = W_hh[(size_t)l * DD + d];
#pragma unroll
            for (int rr = 0; rr < 4; ++rr) acc[rr] += hs[grp * 4 + rr][l] * w;
        }
        float wst = W_st[d], wot = W_ot[d];
#pragma unroll
        for (int rr = 0; rr < 4; ++rr) {
            int r = grp * 4 + rr;
            int e = e0 + r;
            float ns  = sigmoidf_(sDs[r] * wst + acc[rr]);
            float no_ = sigmoidf_(sDo[r] * wot + acc[rr]);
            evt[(size_t)e * FEAT + d]      = ns;
            evt[(size_t)e * FEAT + DD + d] = no_;
            ebuf[(size_t)e * IND + d]      = ns;
            ebuf[(size_t)e * IND + DD + d] = no_;
        }
    }
    // rel section + time_emb + ones
    for (int i = tid; i < 8 * DC; i += 256) {
        int r = i >> 6, c = i & 63;
        float v = xc[r][2 * DD + c];
        int e = e0 + r;
        evt[(size_t)e * FEAT + 2 * DD + c] = v;
        ebuf[(size_t)e * IND + 2 * DD + c] = v;
    }
    for (int i = tid; i < 8 * DD; i += 256) {
        int r = i >> 7, d = i & 127;
        float denom = __powf(1.0e4f, (float)d);     // inf for d>=10 -> 1/inf = 0 (matches ref)
        float v = sinf(sTv[r] * (1.0f / denom));
        int e = e0 + r;
        ebuf[(size_t)e * IND + FEAT + d] = v;
        tebuf[(size_t)e * DD + d] = v;
    }
    if (tid < 8) ebuf[(size_t)(e0 + tid) * IND + FEAT + DD] = 1.0f;
}

// ---------------- K3: fix rounds (collision events, dependency-ordered) ----------------
__global__ __launch_bounds__(256)
void fix_round(int round,
               const int* __restrict__ seq_s, const int* __restrict__ seq_o,
               const float* __restrict__ mem0, const float* __restrict__ W_hidden,
               const float* __restrict__ W_hh, const float* __restrict__ W_st,
               const float* __restrict__ W_ot, const float* __restrict__ slotDt,
               const int* __restrict__ slotPrev, const int* __restrict__ fixList,
               int* __restrict__ fixState, const int* __restrict__ evFixIdx,
               const int* __restrict__ fixCnt,
               float* __restrict__ evt, float* __restrict__ ebuf) {
    __shared__ float xc[FEAT];
    __shared__ float hsv[DL];
    __shared__ float hp[2][DD];
    __shared__ int sGo, sPs, sPo, sE;
    int tid = threadIdx.x;
    int n = *fixCnt;
    for (int f = blockIdx.x; f < n; f += gridDim.x) {
        if (tid == 0) {
            int go = 0, ps = 0, po = 0, e = 0;
            if (fixState[f] == -1) {
                e = fixList[f];
                int b = e >> 6, t = e & 63;
                ps = slotPrev[t * 64 + b];
                po = slotPrev[t * 64 + 32 + b];
                go = 1;
                if (ps >= 0) {
                    int pe = (ps & 31) * 64 + (ps >> 6);
                    int fi = evFixIdx[pe];
                    if (fi >= 0) { int st = fixState[fi]; if (st < 0 || st >= round) go = 0; }
                }
                if (po >= 0) {
                    int pe = (po & 31) * 64 + (po >> 6);
                    int fi = evFixIdx[pe];
                    if (fi >= 0) { int st = fixState[fi]; if (st < 0 || st >= round) go = 0; }
                }
            }
            sGo = go; sPs = ps; sPo = po; sE = e;
        }
        __syncthreads();
        int go = sGo, ps = sPs, po = sPo, e = sE;
        __syncthreads();
        if (!go) continue;
        int b = e >> 6, t = e & 63;
        // gather current inputs
        for (int i = tid; i < FEAT; i += 256) {
            float v;
            if (i < DD) {
                v = (ps >= 0) ? evt[(size_t)((ps & 31) * 64 + (ps >> 6)) * FEAT + ((ps >> 5) & 1) * DD + i]
                              : mem0[(size_t)seq_s[e] * DD + i];
            } else if (i < 2 * DD) {
                int k = i - DD;
                v = (po >= 0) ? evt[(size_t)((po & 31) * 64 + (po >> 6)) * FEAT + ((po >> 5) & 1) * DD + k]
                              : mem0[(size_t)seq_o[e] * DD + k];
            } else {
                v = evt[(size_t)e * FEAT + i];    // rel section (unchanged by fixes)
            }
            xc[i] = v;
        }
        __syncthreads();
        {   // z GEMV with 4-way ILP
            float a0 = 0.f, a1 = 0.f, a2 = 0.f, a3 = 0.f;
            for (int k = 0; k < FEAT; k += 4) {
                a0 += xc[k]     * W_hidden[(size_t)k * DL + tid];
                a1 += xc[k + 1] * W_hidden[(size_t)(k + 1) * DL + tid];
                a2 += xc[k + 2] * W_hidden[(size_t)(k + 2) * DL + tid];
                a3 += xc[k + 3] * W_hidden[(size_t)(k + 3) * DL + tid];
            }
            hsv[tid] = sigmoidf_((a0 + a1) + (a2 + a3));
        }
        __syncthreads();
        {   // hh partials
            int d = tid & 127, g = tid >> 7;
            float a0 = 0.f, a1 = 0.f;
            int l0 = g * 128;
            for (int l = 0; l < 128; l += 2) {
                a0 += hsv[l0 + l]     * W_hh[(size_t)(l0 + l) * DD + d];
                a1 += hsv[l0 + l + 1] * W_hh[(size_t)(l0 + l + 1) * DD + d];
            }
            hp[g][d] = a0 + a1;
        }
        __syncthreads();
        if (tid < DD) {
            float hh = hp[0][tid] + hp[1][tid];
            float ns  = sigmoidf_(slotDt[t * 64 + b]      * W_st[tid] + hh);
            float no_ = sigmoidf_(slotDt[t * 64 + 32 + b] * W_ot[tid] + hh);
            evt[(size_t)e * FEAT + tid]      = ns;
            evt[(size_t)e * FEAT + DD + tid] = no_;
            ebuf[(size_t)e * IND + tid]      = ns;
            ebuf[(size_t)e * IND + DD + tid] = no_;
        }
        __syncthreads();
        __threadfence();
        if (tid == 0) fixState[f] = round;
        __syncthreads();
    }
}

// ---------------- K4: winner scatter to out_mem / out_lt ----------------
__global__ __launch_bounds__(256)
void scatter_win(const int* __restrict__ seq_s, const int* __restrict__ seq_o,
                 const float* __restrict__ seq_time, const int* __restrict__ slotWin,
                 const float* __restrict__ evt, float* __restrict__ out_mem,
                 float* __restrict__ out_lt) {
    int gid = blockIdx.x * 256 + threadIdx.x;   // 131072 = 4096 slots * 32
    int slot = gid >> 5, c = gid & 31;
    if (!slotWin[slot]) return;
    int b = slot & 31, side = (slot >> 5) & 1, t = slot >> 6;
    int e = b * TT + t;
    int ent = (side ? seq_o : seq_s)[e];
    floatx4 v = *(const floatx4*)&evt[(size_t)e * FEAT + side * DD + c * 4];
    *(floatx4*)&out_mem[(size_t)ent * DD + c * 4] = v;
    if (c == 0) out_lt[ent] = seq_time[e];
}

// ---------------- phase 2 ----------------
__global__ __launch_bounds__(256)
void proj(const float* __restrict__ ebuf, const float* __restrict__ Wq,
          const float* __restrict__ Wk, const float* __restrict__ Wv,
          float* __restrict__ q, float* __restrict__ k, float* __restrict__ v) {
    __shared__ float at[32][IND];
    int tid = threadIdx.x;
    int r0b = blockIdx.x * 32;
    for (int i = tid; i < 32 * IND; i += 256) {
        int r = i / IND, c = i - r * IND;
        at[r][c] = ebuf[(size_t)(r0b + r) * IND + c];
    }
    __syncthreads();
    const float* W = (blockIdx.z == 0) ? Wq : (blockIdx.z == 1) ? Wk : Wv;
    float* out = (blockIdx.z == 0) ? q : (blockIdx.z == 1) ? k : v;
    int colg = tid & 15, rowg = tid >> 4;
    int c0 = blockIdx.y * 64 + colg * 4;
    int r0 = rowg * 2;
    floatx4 acc0 = {0.f, 0.f, 0.f, 0.f}, acc1 = {0.f, 0.f, 0.f, 0.f};
    for (int kk = 0; kk < IND; ++kk) {
        floatx4 w = *(const floatx4*)&W[(size_t)kk * FEAT + c0];
        float a0 = at[r0][kk], a1 = at[r0 + 1][kk];
        acc0 += a0 * w;
        acc1 += a1 * w;
    }
    *(floatx4*)&out[(size_t)(r0b + r0) * FEAT + c0]     = acc0;
    *(floatx4*)&out[(size_t)(r0b + r0 + 1) * FEAT + c0] = acc1;
}

__global__ __launch_bounds__(256)
void attn(const float* __restrict__ q, const float* __restrict__ k,
          const float* __restrict__ v, float* __restrict__ ao) {
    __shared__ float qs[TT][DH], ks[TT][DH], vs[TT][DH];
    __shared__ float sc[TT][TT + 1];
    int bh = blockIdx.x;
    int b = bh >> 2, h = bh & 3;
    int tid = threadIdx.x;
    for (int i = tid; i < TT * DH; i += 256) {
        int r = i / DH, d = i - r * DH;
        size_t base = (size_t)(b * TT + r) * FEAT + h * DH + d;
        qs[r][d] = q[base]; ks[r][d] = k[base]; vs[r][d] = v[base];
    }
    __syncthreads();
    const float scale = 0.11180339887498949f;   // 1/sqrt(80)
    for (int idx = tid; idx < TT * TT; idx += 256) {
        int i = idx >> 6, j = idx & 63;
        float s = 0.f;
        for (int d = 0; d < DH; ++d) s += qs[i][d] * ks[j][d];
        sc[i][j] = s * scale;
    }
    __syncthreads();
    if (tid < TT) {
        int i = tid;
        if (i == 0) {
            for (int j = 0; j < TT; ++j) sc[0][j] = 0.0f;
        } else {
            float m = -1e30f;
            for (int j = 0; j < i; ++j) m = fmaxf(m, sc[i][j]);
            float sum = 0.f;
            for (int j = 0; j < i; ++j) { float p = __expf(sc[i][j] - m); sc[i][j] = p; sum += p; }
            float inv = 1.0f / sum;
            for (int j = 0; j < i; ++j) sc[i][j] *= inv;
            for (int j = i; j < TT; ++j) sc[i][j] = 0.0f;
        }
    }
    __syncthreads();
    for (int idx = tid; idx < TT * DH; idx += 256) {
        int i = idx / DH, d = idx - i * DH;
        float s = 0.f;
        for (int j = 0; j < TT; ++j) s += sc[i][j] * vs[j][d];
        ao[(size_t)(b * TT + i) * FEAT + h * DH + d] = s;
    }
}

__global__ __launch_bounds__(256)
void outproj(const float* __restrict__ ain, const float* __restrict__ Wo,
             const float* __restrict__ resid, float* __restrict__ xout,
             float* __restrict__ ebufW, int writeE) {
    __shared__ float at[32][FEAT];
    int tid = threadIdx.x;
    int r0b = blockIdx.x * 32;
    for (int i = tid; i < 32 * FEAT; i += 256) {
        int r = i / FEAT, c = i - r * FEAT;
        at[r][c] = ain[(size_t)(r0b + r) * FEAT + c];
    }
    __syncthreads();
    int colg = tid & 15, rowg = tid >> 4;
    int c0 = blockIdx.y * 64 + colg * 4;
    int r0 = rowg * 2;
    floatx4 acc0 = {0.f, 0.f, 0.f, 0.f}, acc1 = {0.f, 0.f, 0.f, 0.f};
    for (int kk = 0; kk < FEAT; ++kk) {
        floatx4 w = *(const floatx4*)&Wo[(size_t)kk * FEAT + c0];
        float a0 = at[r0][kk], a1 = at[r0 + 1][kk];
        acc0 += a0 * w;
        acc1 += a1 * w;
    }
#pragma unroll
    for (int rr = 0; rr < 2; ++rr) {
        int row = r0b + r0 + rr;
        floatx4 a = rr ? acc1 : acc0;
        floatx4 res = *(const floatx4*)&resid[(size_t)row * FEAT + c0];
        floatx4 o;
#pragma unroll
        for (int i = 0; i < 4; ++i) o[i] = res[i] + tanhf(a[i]);
        *(floatx4*)&xout[(size_t)row * FEAT + c0] = o;
        if (writeE) {
#pragma unroll
            for (int i = 0; i < 4; ++i) ebufW[(size_t)row * IND + c0 + i] = o[i];
        }
    }
}

__global__ __launch_bounds__(128)
void score_k(const float* __restrict__ x, const float* __restrict__ W1,
             const float* __restrict__ b1, const float* __restrict__ W2,
             const float* __restrict__ b2, float* __restrict__ lam_out,
             float* __restrict__ loss_out) {
    __shared__ float xr[FEAT];
    __shared__ float red[2];
    int e = blockIdx.x;
    int tid = threadIdx.x;
    for (int f = tid; f < FEAT; f += 128) xr[f] = x[(size_t)e * FEAT + f];
    __syncthreads();
    int d = tid;
    float acc = b1[d];
    for (int kk = 0; kk < FEAT; ++kk) acc += xr[kk] * W1[kk * DD + d];
    acc = fmaxf(acc, 0.0f) * W2[d];
    for (int off = 32; off; off >>= 1) acc += __shfl_down(acc, off, 64);
    if ((tid & 63) == 0) red[tid >> 6] = acc;
    __syncthreads();
    if (tid == 0) {
        float s = red[0] + red[1] + b2[0];
        float lam = fmaxf(s, 0.0f) + log1pf(expf(-fabsf(s)));   // softplus
        lam_out[e] = lam;
        atomicAdd(loss_out, -logf(lam + 1e-8f) * (1.0f / 2048.0f));
    }
}

// ---------------- launch ----------------
extern "C" void kernel_launch(void* const* d_in, const int* in_sizes, int n_in,
                              void* d_out, int out_size, void* d_ws, size_t ws_size,
                              hipStream_t stream) {
    const int*   seq_s = (const int*)d_in[0];
    const int*   seq_o = (const int*)d_in[1];
    const int*   seq_r = (const int*)d_in[2];
    const float* seq_t = (const float*)d_in[3];
    const float* mem0  = (const float*)d_in[4];
    const float* lt0   = (const float*)d_in[5];
    const float* rel   = (const float*)d_in[6];
    const float* W_hidden = (const float*)d_in[7];
    const float* W_hh  = (const float*)d_in[8];
    const float* W_st  = (const float*)d_in[9];
    const float* W_ot  = (const float*)d_in[10];
    const float* Wq    = (const float*)d_in[11];
    const float* Wk    = (const float*)d_in[12];
    const float* Wv    = (const float*)d_in[13];
    const float* Wo    = (const float*)d_in[14];
    const float* sW1   = (const float*)d_in[15];
    const float* sb1   = (const float*)d_in[16];
    const float* sW2   = (const float*)d_in[17];
    const float* sb2   = (const float*)d_in[18];

    float* out      = (float*)d_out;
    float* out_lam  = out + 1;
    float* out_mem  = out + 2049;
    float* out_lt   = out + 2049 + (size_t)NE * DD;

    float* ws = (float*)d_ws;
    float* evt   = ws;                         // 655360
    float* xbuf  = ws + 655360;                // 655360
    float* ebuf  = ws + 1310720;               // 919552
    float* tebuf = ws + 2230272;               // 262144
    float* qbuf  = ws + 2492416;               // 655360
    float* kbuf  = ws + 3147776;               // 655360
    float* vbuf  = ws + 3803136;               // 655360
    float* aobuf = ws + 4458496;               // 655360
    float* slotDt   = ws + 5113856;            // 4096
    int*   slotPrev = (int*)(ws + 5117952);    // 4096
    int*   slotWin  = (int*)(ws + 5122048);    // 4096
    int*   fixList  = (int*)(ws + 5126144);    // 2048
    int*   fixState = (int*)(ws + 5128192);    // 2048
    int*   evFixIdx = (int*)(ws + 5130240);    // 2048
    int*   fixCnt   = (int*)(ws + 5132288);    // 1

    // Outputs: start from initial state (touched entities overwritten by scatter_win).
    hipMemcpyAsync(out_mem, mem0, (size_t)NE * DD * sizeof(float), hipMemcpyDeviceToDevice, stream);
    hipMemcpyAsync(out_lt,  lt0,  (size_t)NE * sizeof(float),      hipMemcpyDeviceToDevice, stream);
    hipMemsetAsync(fixCnt, 0, sizeof(int), stream);
    hipMemsetAsync(out, 0, sizeof(float), stream);     // loss accumulator

    slot_analyze<<<NSLOT / 256, 256, 0, stream>>>(seq_s, seq_o, seq_t, lt0,
                                                  slotDt, slotPrev, slotWin,
                                                  fixList, fixState, evFixIdx, fixCnt);
    event_compute<<<NEV / 8, 256, 0, stream>>>(seq_s, seq_o, seq_r, seq_t, mem0, rel,
                                               W_hidden, W_hh, W_st, W_ot, slotDt,
                                               evt, ebuf, tebuf);
    for (int r = 0; r < 4; ++r)
        fix_round<<<64, 256, 0, stream>>>(r, seq_s, seq_o, mem0, W_hidden, W_hh,
                                          W_st, W_ot, slotDt, slotPrev,
                                          fixList, fixState, evFixIdx, fixCnt, evt, ebuf);
    scatter_win<<<512, 256, 0, stream>>>(seq_s, seq_o, seq_t, slotWin, evt, out_mem, out_lt);

    for (int l = 0; l < 2; ++l) {
        const float* src = l ? xbuf : evt;     // residual input
        proj<<<dim3(64, 5, 3), 256, 0, stream>>>(ebuf,
                                                 Wq + (size_t)l * IND * FEAT,
                                                 Wk + (size_t)l * IND * FEAT,
                                                 Wv + (size_t)l * IND * FEAT,
                                                 qbuf, kbuf, vbuf);
        attn<<<128, 256, 0, stream>>>(qbuf, kbuf, vbuf, aobuf);
        outproj<<<dim3(64, 5), 256, 0, stream>>>(aobuf, Wo + (size_t)l * FEAT * FEAT,
                                                 src, xbuf, ebuf, (l == 0) ? 1 : 0);
    }
    score_k<<<NEV, 128, 0, stream>>>(xbuf, sW1, sb1, sW2, sb2, out_lam, out);
}